// Round 2
// baseline (6546.781 us; speedup 1.0000x reference)
//
#include <hip/hip_runtime.h>

#define NN 50000
#define NE 800000

// ---------------- LayerNorm: one wave (64 lanes) per node, 128 cols ----------
__global__ __launch_bounds__(256) void ln_kernel(
    const float* __restrict__ x, const float* __restrict__ g,
    const float* __restrict__ b, float* __restrict__ h, int n) {
  int wid  = (blockIdx.x * blockDim.x + threadIdx.x) >> 6;
  int lane = threadIdx.x & 63;
  if (wid >= n) return;
  const float2 v = *(const float2*)(x + (size_t)wid * 128 + lane * 2);
  float sum = v.x + v.y;
  float sq  = v.x * v.x + v.y * v.y;
#pragma unroll
  for (int off = 32; off > 0; off >>= 1) {
    sum += __shfl_down(sum, off);
    sq  += __shfl_down(sq, off);
  }
  sum = __shfl(sum, 0);
  sq  = __shfl(sq, 0);
  float mu  = sum * (1.f / 128.f);
  float var = sq * (1.f / 128.f) - mu * mu;
  float inv = rsqrtf(var + 1e-5f);
  float2 gg = *(const float2*)(g + lane * 2);
  float2 bb = *(const float2*)(b + lane * 2);
  float2 o;
  o.x = (v.x - mu) * inv * gg.x + bb.x;
  o.y = (v.y - mu) * inv * gg.y + bb.y;
  *(float2*)(h + (size_t)wid * 128 + lane * 2) = o;
}

// ---------------- Generic K=128 fp32 GEMM: Out = A(Mx128) @ W(128xNw) + bias (+resid)
// BM=128, BN=64, BK=64, 256 threads, TM=8 x TN=4 per thread.
__global__ __launch_bounds__(256) void gemm128(
    const float* __restrict__ A, const float* __restrict__ W,
    const float* __restrict__ bias, const float* __restrict__ resid,
    float* __restrict__ Out, int M, int Nw) {
  __shared__ float As[128][65];   // +1 pad: scalar reads As[row][k] conflict-free
  __shared__ float Bs[64][64];    // float4-friendly

  int tid = threadIdx.x;
  int ty  = tid >> 4;   // 0..15 -> 8 rows each
  int tx  = tid & 15;   // 0..15 -> 4 cols each
  int m0  = blockIdx.x * 128;
  int n0  = blockIdx.y * 64;

  float acc[8][4] = {};

  for (int kb = 0; kb < 128; kb += 64) {
#pragma unroll
    for (int i = 0; i < 8; ++i) {            // A tile: 128 rows x 64 k
      int c = tid + i * 256;                 // 0..2047
      int row = c >> 4, kv = c & 15;
      float4 av = make_float4(0.f, 0.f, 0.f, 0.f);
      if (m0 + row < M)
        av = *(const float4*)(A + (size_t)(m0 + row) * 128 + kb + kv * 4);
      As[row][kv * 4 + 0] = av.x;
      As[row][kv * 4 + 1] = av.y;
      As[row][kv * 4 + 2] = av.z;
      As[row][kv * 4 + 3] = av.w;
    }
    // B tile: 64 k-rows x 64 cols = 1024 float4 -> 256 threads x 4 iters
    // (R1 bug: i<2 left k-rows 32..63 uninitialized -> absmax 1.2e4)
#pragma unroll
    for (int i = 0; i < 4; ++i) {
      int c = tid + i * 256;                 // 0..1023
      int kr = c >> 4, nv = c & 15;          // kr 0..63, nv 0..15
      float4 bv = *(const float4*)(W + (size_t)(kb + kr) * Nw + n0 + nv * 4);
      *(float4*)&Bs[kr][nv * 4] = bv;
    }
    __syncthreads();
#pragma unroll
    for (int k = 0; k < 64; ++k) {
      float4 bv = *(float4*)&Bs[k][tx * 4];
#pragma unroll
      for (int j = 0; j < 8; ++j) {
        float a = As[ty * 8 + j][k];
        acc[j][0] += a * bv.x;
        acc[j][1] += a * bv.y;
        acc[j][2] += a * bv.z;
        acc[j][3] += a * bv.w;
      }
    }
    __syncthreads();
  }

  float4 bb = *(const float4*)(bias + n0 + tx * 4);
#pragma unroll
  for (int j = 0; j < 8; ++j) {
    int row = m0 + ty * 8 + j;
    if (row < M) {
      float4 o;
      o.x = acc[j][0] + bb.x;
      o.y = acc[j][1] + bb.y;
      o.z = acc[j][2] + bb.z;
      o.w = acc[j][3] + bb.w;
      if (resid) {
        float4 r = *(const float4*)(resid + (size_t)row * Nw + n0 + tx * 4);
        o.x += r.x; o.y += r.y; o.z += r.z; o.w += r.w;
      }
      *(float4*)(Out + (size_t)row * Nw + n0 + tx * 4) = o;
    }
  }
}

// monotonic uint encoding of float for atomicMax (0 == "-inf")
__device__ __forceinline__ unsigned int enc_f(float f) {
  unsigned int u = __float_as_uint(f);
  return (u & 0x80000000u) ? ~u : (u | 0x80000000u);
}
__device__ __forceinline__ float dec_f(unsigned int e) {
  return (e & 0x80000000u) ? __uint_as_float(e & 0x7FFFFFFFu)
                           : __uint_as_float(~e);
}

// ---------- pass A: scores + segment max (one thread per edge-head) ----------
__global__ __launch_bounds__(256) void edge_scores(
    const float* __restrict__ qkv, const float* __restrict__ edge_attr,
    const int* __restrict__ ei, float* __restrict__ scores,
    unsigned int* __restrict__ m_enc, int E) {
  int t = blockIdx.x * blockDim.x + threadIdx.x;
  if (t >= E * 8) return;
  int e  = t >> 3;
  int hh = t & 7;
  int src = ei[e];
  int dst = ei[E + e];
  const float* qp = qkv + (size_t)dst * 384 + hh * 16;        // q block
  const float* kp = qkv + (size_t)src * 384 + 128 + hh * 16;  // k block
  const float* ep = edge_attr + (size_t)e * 128 + hh * 16;
  float acc = 0.f;
#pragma unroll
  for (int i = 0; i < 4; ++i) {
    float4 qv = *(const float4*)(qp + i * 4);
    float4 kv = *(const float4*)(kp + i * 4);
    float4 ev = *(const float4*)(ep + i * 4);
    acc += qv.x * (kv.x + ev.x) + qv.y * (kv.y + ev.y) +
           qv.z * (kv.z + ev.z) + qv.w * (kv.w + ev.w);
  }
  acc *= 0.25f;  // D_HEAD^-0.5, D_HEAD=16
  scores[t] = acc;
  atomicMax(&m_enc[(size_t)dst * 8 + hh], enc_f(acc));
}

// ---------- pass B: e = exp(score - m), segment sum -------------------------
__global__ __launch_bounds__(256) void edge_exp(
    const int* __restrict__ ei, float* __restrict__ scores,
    const unsigned int* __restrict__ m_enc, float* __restrict__ s_sum, int E) {
  int t = blockIdx.x * blockDim.x + threadIdx.x;
  if (t >= E * 8) return;
  int e  = t >> 3;
  int hh = t & 7;
  int dst = ei[E + e];
  float m  = dec_f(m_enc[(size_t)dst * 8 + hh]);  // finite: dst has >=1 edge
  float ex = __expf(scores[t] - m);
  scores[t] = ex;
  atomicAdd(&s_sum[(size_t)dst * 8 + hh], ex);
}

// ---------- pass C: attn = e/s, agg += v[src]*attn --------------------------
__global__ __launch_bounds__(256) void edge_msg(
    const float* __restrict__ qkv, const int* __restrict__ ei,
    const float* __restrict__ scores, const float* __restrict__ s_sum,
    float* __restrict__ agg, int E) {
  int t = blockIdx.x * blockDim.x + threadIdx.x;
  if (t >= E * 8) return;
  int e  = t >> 3;
  int hh = t & 7;
  int src = ei[e];
  int dst = ei[E + e];
  float sv   = s_sum[(size_t)dst * 8 + hh];
  float attn = scores[t] / fmaxf(sv, 1e-16f);
  const float* vp = qkv + (size_t)src * 384 + 256 + hh * 16;  // v block
  float* ap = agg + (size_t)dst * 128 + hh * 16;
  float4 v0 = *(const float4*)(vp + 0);
  float4 v1 = *(const float4*)(vp + 4);
  float4 v2 = *(const float4*)(vp + 8);
  float4 v3 = *(const float4*)(vp + 12);
  atomicAdd(ap + 0,  v0.x * attn); atomicAdd(ap + 1,  v0.y * attn);
  atomicAdd(ap + 2,  v0.z * attn); atomicAdd(ap + 3,  v0.w * attn);
  atomicAdd(ap + 4,  v1.x * attn); atomicAdd(ap + 5,  v1.y * attn);
  atomicAdd(ap + 6,  v1.z * attn); atomicAdd(ap + 7,  v1.w * attn);
  atomicAdd(ap + 8,  v2.x * attn); atomicAdd(ap + 9,  v2.y * attn);
  atomicAdd(ap + 10, v2.z * attn); atomicAdd(ap + 11, v2.w * attn);
  atomicAdd(ap + 12, v3.x * attn); atomicAdd(ap + 13, v3.y * attn);
  atomicAdd(ap + 14, v3.z * attn); atomicAdd(ap + 15, v3.w * attn);
}

extern "C" void kernel_launch(void* const* d_in, const int* in_sizes, int n_in,
                              void* d_out, int out_size, void* d_ws,
                              size_t ws_size, hipStream_t stream) {
  const float* x         = (const float*)d_in[0];
  const float* edge_attr = (const float*)d_in[1];
  const float* qkv_w     = (const float*)d_in[2];
  const float* qkv_b     = (const float*)d_in[3];
  const float* out_w     = (const float*)d_in[4];
  const float* out_b     = (const float*)d_in[5];
  const float* ln_g      = (const float*)d_in[6];
  const float* ln_b      = (const float*)d_in[7];
  const int*   ei        = (const int*)d_in[8];
  float* out = (float*)d_out;

  const int N = NN, E = NE;
  float* h        = (float*)d_ws;                       // N*128
  float* qkv      = h + (size_t)N * 128;                // N*384
  float* scores   = qkv + (size_t)N * 384;              // E*8
  unsigned int* m_enc = (unsigned int*)(scores + (size_t)E * 8); // N*8
  float* s_sum    = (float*)(m_enc + (size_t)N * 8);    // N*8
  float* agg      = h;  // h dead after GEMM1; reuse as agg (N*128)

  // 1. LayerNorm
  ln_kernel<<<(N * 64 + 255) / 256, 256, 0, stream>>>(x, ln_g, ln_b, h, N);

  // 2. QKV projection
  dim3 g1((N + 127) / 128, 384 / 64);
  gemm128<<<g1, 256, 0, stream>>>(h, qkv_w, qkv_b, nullptr, qkv, N, 384);

  // 3. init reductions (agg memset MUST follow GEMM1 — aliases h)
  hipMemsetAsync(m_enc, 0, (size_t)N * 8 * 4, stream);
  hipMemsetAsync(s_sum, 0, (size_t)N * 8 * 4, stream);
  hipMemsetAsync(agg,   0, (size_t)N * 128 * 4, stream);

  // 4-6. edge passes
  int tEH = E * 8;
  int nb  = (tEH + 255) / 256;
  edge_scores<<<nb, 256, 0, stream>>>(qkv, edge_attr, ei, scores, m_enc, E);
  edge_exp<<<nb, 256, 0, stream>>>(ei, scores, m_enc, s_sum, E);
  edge_msg<<<nb, 256, 0, stream>>>(qkv, ei, scores, s_sum, agg, E);

  // 7. output projection + bias + residual
  dim3 g2((N + 127) / 128, 128 / 64);
  gemm128<<<g2, 256, 0, stream>>>(agg, out_w, out_b, x, out, N, 128);
}

// Round 3
// 978.157 us; speedup vs baseline: 6.6930x; 6.6930x over previous
//
#include <hip/hip_runtime.h>

#define NN 50000
#define NE 800000

// ---------------- LayerNorm: one wave (64 lanes) per node, 128 cols ----------
__global__ __launch_bounds__(256) void ln_kernel(
    const float* __restrict__ x, const float* __restrict__ g,
    const float* __restrict__ b, float* __restrict__ h, int n) {
  int wid  = (blockIdx.x * blockDim.x + threadIdx.x) >> 6;
  int lane = threadIdx.x & 63;
  if (wid >= n) return;
  const float2 v = *(const float2*)(x + (size_t)wid * 128 + lane * 2);
  float sum = v.x + v.y;
  float sq  = v.x * v.x + v.y * v.y;
#pragma unroll
  for (int off = 32; off > 0; off >>= 1) {
    sum += __shfl_down(sum, off);
    sq  += __shfl_down(sq, off);
  }
  sum = __shfl(sum, 0);
  sq  = __shfl(sq, 0);
  float mu  = sum * (1.f / 128.f);
  float var = sq * (1.f / 128.f) - mu * mu;
  float inv = rsqrtf(var + 1e-5f);
  float2 gg = *(const float2*)(g + lane * 2);
  float2 bb = *(const float2*)(b + lane * 2);
  float2 o;
  o.x = (v.x - mu) * inv * gg.x + bb.x;
  o.y = (v.y - mu) * inv * gg.y + bb.y;
  *(float2*)(h + (size_t)wid * 128 + lane * 2) = o;
}

// ---------------- Generic K=128 fp32 GEMM: Out = A(Mx128) @ W(128xNw) + bias (+resid)
__global__ __launch_bounds__(256) void gemm128(
    const float* __restrict__ A, const float* __restrict__ W,
    const float* __restrict__ bias, const float* __restrict__ resid,
    float* __restrict__ Out, int M, int Nw) {
  __shared__ float As[128][65];
  __shared__ float Bs[64][64];

  int tid = threadIdx.x;
  int ty  = tid >> 4;
  int tx  = tid & 15;
  int m0  = blockIdx.x * 128;
  int n0  = blockIdx.y * 64;

  float acc[8][4] = {};

  for (int kb = 0; kb < 128; kb += 64) {
#pragma unroll
    for (int i = 0; i < 8; ++i) {
      int c = tid + i * 256;
      int row = c >> 4, kv = c & 15;
      float4 av = make_float4(0.f, 0.f, 0.f, 0.f);
      if (m0 + row < M)
        av = *(const float4*)(A + (size_t)(m0 + row) * 128 + kb + kv * 4);
      As[row][kv * 4 + 0] = av.x;
      As[row][kv * 4 + 1] = av.y;
      As[row][kv * 4 + 2] = av.z;
      As[row][kv * 4 + 3] = av.w;
    }
#pragma unroll
    for (int i = 0; i < 4; ++i) {
      int c = tid + i * 256;
      int kr = c >> 4, nv = c & 15;
      float4 bv = *(const float4*)(W + (size_t)(kb + kr) * Nw + n0 + nv * 4);
      *(float4*)&Bs[kr][nv * 4] = bv;
    }
    __syncthreads();
#pragma unroll
    for (int k = 0; k < 64; ++k) {
      float4 bv = *(float4*)&Bs[k][tx * 4];
#pragma unroll
      for (int j = 0; j < 8; ++j) {
        float a = As[ty * 8 + j][k];
        acc[j][0] += a * bv.x;
        acc[j][1] += a * bv.y;
        acc[j][2] += a * bv.z;
        acc[j][3] += a * bv.w;
      }
    }
    __syncthreads();
  }

  float4 bb = *(const float4*)(bias + n0 + tx * 4);
#pragma unroll
  for (int j = 0; j < 8; ++j) {
    int row = m0 + ty * 8 + j;
    if (row < M) {
      float4 o;
      o.x = acc[j][0] + bb.x;
      o.y = acc[j][1] + bb.y;
      o.z = acc[j][2] + bb.z;
      o.w = acc[j][3] + bb.w;
      if (resid) {
        float4 r = *(const float4*)(resid + (size_t)row * Nw + n0 + tx * 4);
        o.x += r.x; o.y += r.y; o.z += r.z; o.w += r.w;
      }
      *(float4*)(Out + (size_t)row * Nw + n0 + tx * 4) = o;
    }
  }
}

// ---------------- CSR build ----------------
__global__ __launch_bounds__(256) void count_kernel(
    const int* __restrict__ ei, int* __restrict__ cnt, int E) {
  int e = blockIdx.x * blockDim.x + threadIdx.x;
  if (e >= E) return;
  atomicAdd(&cnt[ei[E + e]], 1);  // dst row
}

// single-block exclusive scan of cnt[0..n) -> row_start[0..n]
__global__ __launch_bounds__(1024) void scan_kernel(
    const int* __restrict__ cnt, int* __restrict__ row_start, int n) {
  __shared__ int sums[1024];
  int tid = threadIdx.x;
  const int CH = (n + 1023) / 1024;
  int begin = tid * CH;
  int end   = min(begin + CH, n);
  int s = 0;
  for (int i = begin; i < end; ++i) s += cnt[i];
  sums[tid] = s;
  __syncthreads();
  for (int off = 1; off < 1024; off <<= 1) {
    int t = (tid >= off) ? sums[tid - off] : 0;
    __syncthreads();
    if (tid >= off) sums[tid] += t;
    __syncthreads();
  }
  int run = sums[tid] - s;  // exclusive prefix at chunk start
  for (int i = begin; i < end; ++i) {
    row_start[i] = run;
    run += cnt[i];
  }
  if (tid == 1023) row_start[n] = run;  // total (= E)
}

__global__ __launch_bounds__(256) void scatter_kernel(
    const int* __restrict__ ei, int* __restrict__ cursor,
    int* __restrict__ perm, int E) {
  int e = blockIdx.x * blockDim.x + threadIdx.x;
  if (e >= E) return;
  int pos = atomicAdd(&cursor[ei[E + e]], 1);
  perm[pos] = e;
}

// ---------------- Fused per-node attention (online softmax, no atomics) -----
// One wave per node. Lane l: head hg=l>>3, dims d=2*(l&7)..+1 of that head.
__global__ __launch_bounds__(256) void fused_attn(
    const float* __restrict__ qkv, const float* __restrict__ edge_attr,
    const int* __restrict__ ei, const int* __restrict__ row_start,
    const int* __restrict__ perm, float* __restrict__ agg, int N, int E) {
  int node = (blockIdx.x * blockDim.x + threadIdx.x) >> 6;
  if (node >= N) return;
  int lane = threadIdx.x & 63;
  int hg   = lane >> 3;       // head 0..7
  int sub  = lane & 7;        // 0..7 -> dims 2*sub, 2*sub+1
  int ch   = hg * 16 + sub * 2;  // channel 0..127 (bijective over lanes)

  float2 q2 = *(const float2*)(qkv + (size_t)node * 384 + ch);

  float m = -INFINITY, l = 0.f;
  float2 acc = make_float2(0.f, 0.f);

  int beg  = row_start[node];
  int stop = row_start[node + 1];
  for (int i = beg; i < stop; ++i) {
    int e   = perm[i];
    int src = ei[e];
    float2 kv = *(const float2*)(qkv + (size_t)src * 384 + 128 + ch);
    float2 ea = *(const float2*)(edge_attr + (size_t)e * 128 + ch);
    float p = q2.x * (kv.x + ea.x) + q2.y * (kv.y + ea.y);
    p += __shfl_xor(p, 1);
    p += __shfl_xor(p, 2);
    p += __shfl_xor(p, 4);     // sum over the 8 lanes of this head group
    float s  = p * 0.25f;      // D_HEAD^-0.5
    float mn = fmaxf(m, s);
    float scale = __expf(m - mn);   // m=-inf on first edge -> 0, no NaN
    float pe    = __expf(s - mn);
    l = l * scale + pe;
    float2 vv = *(const float2*)(qkv + (size_t)src * 384 + 256 + ch);
    acc.x = acc.x * scale + pe * vv.x;
    acc.y = acc.y * scale + pe * vv.y;
    m = mn;
  }
  float inv = 1.f / fmaxf(l, 1e-16f);
  float2 o = make_float2(acc.x * inv, acc.y * inv);
  *(float2*)(agg + (size_t)node * 128 + ch) = o;
}

extern "C" void kernel_launch(void* const* d_in, const int* in_sizes, int n_in,
                              void* d_out, int out_size, void* d_ws,
                              size_t ws_size, hipStream_t stream) {
  const float* x         = (const float*)d_in[0];
  const float* edge_attr = (const float*)d_in[1];
  const float* qkv_w     = (const float*)d_in[2];
  const float* qkv_b     = (const float*)d_in[3];
  const float* out_w     = (const float*)d_in[4];
  const float* out_b     = (const float*)d_in[5];
  const float* ln_g      = (const float*)d_in[6];
  const float* ln_b      = (const float*)d_in[7];
  const int*   ei        = (const int*)d_in[8];
  float* out = (float*)d_out;

  const int N = NN, E = NE;
  float* h         = (float*)d_ws;                        // N*128 f
  float* qkv       = h + (size_t)N * 128;                 // N*384 f
  int*   cnt       = (int*)(qkv + (size_t)N * 384);       // N
  int*   row_start = cnt + N;                             // N+1
  int*   cursor    = row_start + N + 1;                   // N
  int*   perm      = cursor + N;                          // E
  float* agg       = h;  // h dead after GEMM1; fused_attn writes (no memset)

  // --- CSR build (independent of LN/GEMM, same stream => ordered) ---
  hipMemsetAsync(cnt, 0, (size_t)N * 4, stream);
  count_kernel<<<(E + 255) / 256, 256, 0, stream>>>(ei, cnt, E);
  scan_kernel<<<1, 1024, 0, stream>>>(cnt, row_start, N);
  hipMemcpyAsync(cursor, row_start, (size_t)N * 4, hipMemcpyDeviceToDevice,
                 stream);
  scatter_kernel<<<(E + 255) / 256, 256, 0, stream>>>(ei, cursor, perm, E);

  // --- 1. LayerNorm ---
  ln_kernel<<<(N * 64 + 255) / 256, 256, 0, stream>>>(x, ln_g, ln_b, h, N);

  // --- 2. QKV projection ---
  dim3 g1((N + 127) / 128, 384 / 64);
  gemm128<<<g1, 256, 0, stream>>>(h, qkv_w, qkv_b, nullptr, qkv, N, 384);

  // --- 3. fused attention (scores + softmax + aggregate) ---
  fused_attn<<<(N * 64 + 255) / 256, 256, 0, stream>>>(
      qkv, edge_attr, ei, row_start, perm, agg, N, E);

  // --- 4. output projection + bias + residual ---
  dim3 g2((N + 127) / 128, 128 / 64);
  gemm128<<<g2, 256, 0, stream>>>(agg, out_w, out_b, x, out, N, 128);
}